// Round 8
// baseline (500.289 us; speedup 1.0000x reference)
//
#include <hip/hip_runtime.h>

#define BS 65536
#define DIM 64
#define SD 1024
#define TM 32
#define NTHREADS 512
#define NBLK 512
#define NCHUNK 4
#define TILE 128
#define NTILES 8
#define SROWB 2064        // bytes per S row: 1024 f16 + 16B pad
#define LOG2E 1.44269504f
#define LN2   0.69314718f
#define GS2   24.0f       // gumbel shift in log2 units; cancels in normalization

// LDS layout (bytes)
#define L_S      0         // [32] rows x 2064B: f16 log2-scores -> bf16 ey (in-place)
#define L_C2S    66048     // [1024] f32
#define L_PAV    70144     // [1024] f32 block avg-prob accumulator
#define L_Z2S    74240     // [32] f32
#define L_ZYS    74368     // [32] f32
#define L_RMXP   74496     // [4][32] f32 per-colgroup row-max partials
#define L_WRED   75008     // [8] f32
#define LDS_BYTES 75072

// workspace layout (bytes)
#define WS_CBP   0          // 8 tiles x [128 rows x 144B: 64 bf16 + pad]
#define WS_CBT   147456     // 8 tiles x [64 rows(d) x 272B: 128 bf16 + pad]
#define WS_C2    286720     // [1024] f32
#define WS_AVG   290816     // [1024] f32 accumulator (zeroed by prep)
#define WS_APART 294912     // [512][1024] f32 per-block avg partials
#define WS_LPART 2392064    // [512] f32 per-block loss partials

typedef __attribute__((ext_vector_type(8))) short bf16x8;
typedef __attribute__((ext_vector_type(4))) float f32x4;
typedef __attribute__((ext_vector_type(4))) _Float16 f16x4;

__device__ __forceinline__ unsigned short f2bf(float f) {
  union { float f; unsigned int u; } v; v.f = f;
  unsigned int r = v.u + 0x7fffu + ((v.u >> 16) & 1u);
  return (unsigned short)(r >> 16);
}
__device__ __forceinline__ float wsum64(float v) {
  #pragma unroll
  for (int m = 1; m < 64; m <<= 1) v += __shfl_xor(v, m);
  return v;
}
__device__ __forceinline__ bf16x8 pack8(float4 a, float4 b) {
  bf16x8 r;
  r[0]=(short)f2bf(a.x); r[1]=(short)f2bf(a.y); r[2]=(short)f2bf(a.z); r[3]=(short)f2bf(a.w);
  r[4]=(short)f2bf(b.x); r[5]=(short)f2bf(b.y); r[6]=(short)f2bf(b.z); r[7]=(short)f2bf(b.w);
  return r;
}
// LDS-visibility barrier: does NOT drain vmcnt -> global loads stay in flight
__device__ __forceinline__ void bar() {
  asm volatile("s_waitcnt lgkmcnt(0)" ::: "memory");
  __builtin_amdgcn_s_barrier();
  asm volatile("" ::: "memory");
}

// ---------------- prep: padded bf16 codebook tiles (+transposed), c2, zero avgg ----------------
__global__ __launch_bounds__(256) void gvq_prep(const float* __restrict__ cb, char* __restrict__ ws) {
  int gid = blockIdx.x * 256 + threadIdx.x;   // 0..16383
  int j = gid >> 4, dg = gid & 15;
  float4 v = *(const float4*)(cb + j * DIM + dg * 4);
  float s = v.x*v.x + v.y*v.y + v.z*v.z + v.w*v.w;
  s += __shfl_xor(s, 1); s += __shfl_xor(s, 2); s += __shfl_xor(s, 4); s += __shfl_xor(s, 8);
  int tt = j >> 7, jl = j & 127;
  unsigned short b0 = f2bf(v.x), b1 = f2bf(v.y), b2 = f2bf(v.z), b3 = f2bf(v.w);
  uint2 pk;
  pk.x = (unsigned)b0 | ((unsigned)b1 << 16);
  pk.y = (unsigned)b2 | ((unsigned)b3 << 16);
  *(uint2*)(ws + WS_CBP + tt * 18432 + jl * 144 + dg * 8) = pk;
  unsigned short* tb = (unsigned short*)(ws + WS_CBT + tt * 17408 + jl * 2);
  int d = dg * 4;            // 272B rows = 136 u16 stride
  tb[(d + 0) * 136] = b0; tb[(d + 1) * 136] = b1;
  tb[(d + 2) * 136] = b2; tb[(d + 3) * 136] = b3;
  if (dg == 0) ((float*)(ws + WS_C2))[j] = s;
  if (gid < SD) ((float*)(ws + WS_AVG))[gid] = 0.f;
}

// ---------------- main fused kernel: 512 blocks x 4 chunks, 2 blocks/CU ----------------
__global__ __launch_bounds__(NTHREADS, 2) void gvq_main(
    const float* __restrict__ z, const float* __restrict__ pq,
    const float* __restrict__ u, char* __restrict__ ws,
    float* __restrict__ out)
{
  extern __shared__ char smem[];
  char*  Sb     = smem + L_S;
  float* c2s    = (float*)(smem + L_C2S);
  float* pavacc = (float*)(smem + L_PAV);
  float* z2s    = (float*)(smem + L_Z2S);
  float* zys    = (float*)(smem + L_ZYS);
  float* rmxp   = (float*)(smem + L_RMXP);
  float* wred   = (float*)(smem + L_WRED);

  const int t    = threadIdx.x;
  const int lane = t & 63;
  const int wave = t >> 6;
  const int l15  = lane & 15;
  const int lg   = lane >> 4;
  const int rb   = wave & 1;   // 16-row half
  const int cgrp = wave >> 1;  // PA 32-col group / PD 16-dim group
  const int lr0  = wave * 4;   // PB row base

  const char* cbbp = ws + WS_CBP;
  const char* cbtp = ws + WS_CBT;
  const float* c2g = (const float*)(ws + WS_C2);
  float* apart     = (float*)(ws + WS_APART);
  float* lpart     = (float*)(ws + WS_LPART);

  const float weight  = 0.5f / fmaxf(pq[0], 1e-10f);
  const float weight2 = weight * LOG2E;   // log2-domain scale

  c2s[t] = c2g[t]; c2s[t + 512] = c2g[t + 512];
  pavacc[t] = 0.f; pavacc[t + 512] = 0.f;

  float kd_acc = 0.f, kc_acc = 0.f;

  const int paOff = (cgrp * 32 + l15) * 144 + lg * 16;   // + tt*18432 + cbk*2304 + half*64
  const int pdOff = (cgrp * 16 + l15) * 272 + lg * 16;   // + tt*17408 + kb*64

  // prefetch u row0 of chunk 0
  float4 ua0, ua1, ua2, ua3;
  {
    const float* ur = u + (size_t)(blockIdx.x * NCHUNK * TM + lr0) * SD + 4 * lane;
    ua0 = *(const float4*)(ur);
    ua1 = *(const float4*)(ur + 256);
    ua2 = *(const float4*)(ur + 512);
    ua3 = *(const float4*)(ur + 768);
  }

  for (int c = 0; c < NCHUNK; ++c) {
    const int r0 = (blockIdx.x * NCHUNK + c) * TM;

    // ---- P0: z A-frags direct from global, z2 ----
    const int arow = r0 + rb * 16 + l15;
    float4 za = *(const float4*)(z + (size_t)arow * DIM + lg * 8);
    float4 zb = *(const float4*)(z + (size_t)arow * DIM + lg * 8 + 4);
    float4 zc = *(const float4*)(z + (size_t)arow * DIM + 32 + lg * 8);
    float4 zd = *(const float4*)(z + (size_t)arow * DIM + 32 + lg * 8 + 4);
    bf16x8 a0 = pack8(za, zb);
    bf16x8 a1 = pack8(zc, zd);
    float zsq = za.x*za.x+za.y*za.y+za.z*za.z+za.w*za.w
              + zb.x*zb.x+zb.y*zb.y+zb.z*zb.z+zb.w*zb.w
              + zc.x*zc.x+zc.y*zc.y+zc.z*zc.z+zc.w*zc.w
              + zd.x*zd.x+zd.y*zd.y+zd.z*zd.z+zd.w*zd.w;
    zsq += __shfl_xor(zsq, 16); zsq += __shfl_xor(zsq, 32);
    if (lg == 0) z2s[rb * 16 + l15] = zsq;
    bar();  // prev chunk's S/zys reads done; z2s visible

    // ---- PA: S(f16, log2 units) = -w2*(z2 + c2 - 2*z.c); 1-deep tile rotation ----
#define PALD(tt, cbk, half) (*(const bf16x8*)(cbbp + (tt) * 18432 + (cbk) * 2304 + (half) * 64 + paOff))
    float rmax[4] = {-1e30f, -1e30f, -1e30f, -1e30f};
    bf16x8 c00 = PALD(0,0,0), c01 = PALD(0,0,1), c10 = PALD(0,1,0), c11 = PALD(0,1,1);
    for (int tt = 0; tt < NTILES; ++tt) {
      bf16x8 n00, n01, n10, n11;
      if (tt + 1 < NTILES) {
        n00 = PALD(tt+1,0,0); n01 = PALD(tt+1,0,1);
        n10 = PALD(tt+1,1,0); n11 = PALD(tt+1,1,1);
      }
      #pragma unroll
      for (int cbk = 0; cbk < 2; ++cbk) {
        f32x4 acc = {0.f, 0.f, 0.f, 0.f};
        acc = __builtin_amdgcn_mfma_f32_16x16x32_bf16(a0, cbk ? c10 : c00, acc, 0, 0, 0);
        acc = __builtin_amdgcn_mfma_f32_16x16x32_bf16(a1, cbk ? c11 : c01, acc, 0, 0, 0);
        int jg = tt * TILE + cgrp * 32 + cbk * 16 + l15;
        float c2v = c2s[jg];
        int rl = rb * 16 + lg * 4;
        #pragma unroll
        for (int rr = 0; rr < 4; ++rr) {
          float logit = -weight2 * (z2s[rl + rr] + c2v - 2.f * acc[rr]);
          *(_Float16*)(Sb + (rl + rr) * SROWB + jg * 2) = (_Float16)logit;
          rmax[rr] = fmaxf(rmax[rr], logit);
        }
      }
      c00 = n00; c01 = n01; c10 = n10; c11 = n11;
    }
#undef PALD
    #pragma unroll
    for (int rr = 0; rr < 4; ++rr) {
      float v = rmax[rr];
      v = fmaxf(v, __shfl_xor(v, 1)); v = fmaxf(v, __shfl_xor(v, 2));
      v = fmaxf(v, __shfl_xor(v, 4)); v = fmaxf(v, __shfl_xor(v, 8));
      if (l15 == 0) rmxp[cgrp * 32 + rb * 16 + lg * 4 + rr] = v;
    }
    bar();  // S + rmxp visible

    // ---- PB: sweep1 stats (read-only), sweep2 recompute+gumbel+pav-atomic ----
    #pragma unroll
    for (int rr = 0; rr < 4; ++rr) {
      const int lr = lr0 + rr;
      char* Srow = Sb + lr * SROWB;
      // issue next-row u prefetch early (hidden under both sweeps)
      float4 un0 = ua0, un1 = ua1, un2 = ua2, un3 = ua3;
      if (rr < 3) {
        const float* un = u + (size_t)(r0 + lr + 1) * SD + 4 * lane;
        un0 = *(const float4*)(un);
        un1 = *(const float4*)(un + 256);
        un2 = *(const float4*)(un + 512);
        un3 = *(const float4*)(un + 768);
      } else if (c + 1 < NCHUNK) {
        const float* un = u + (size_t)(r0 + TM + lr0) * SD + 4 * lane;
        un0 = *(const float4*)(un);
        un1 = *(const float4*)(un + 256);
        un2 = *(const float4*)(un + 512);
        un3 = *(const float4*)(un + 768);
      }
      const float m = fmaxf(fmaxf(rmxp[lr], rmxp[32 + lr]),
                            fmaxf(rmxp[64 + lr], rmxp[96 + lr]));
      // sweep 1: Zs, E1 (log2 domain), no writes
      float Zs = 0.f, E1 = 0.f;
      #pragma unroll
      for (int K = 0; K < 4; ++K) {
        f16x4 s4 = *(const f16x4*)(Srow + K * 512 + 8 * lane);
        float d0 = (float)s4[0] - m, d1 = (float)s4[1] - m;
        float d2 = (float)s4[2] - m, d3 = (float)s4[3] - m;
        float e0 = __builtin_amdgcn_exp2f(d0), e1 = __builtin_amdgcn_exp2f(d1);
        float e2 = __builtin_amdgcn_exp2f(d2), e3 = __builtin_amdgcn_exp2f(d3);
        Zs += (e0 + e1) + (e2 + e3);
        E1 += (e0 * d0 + e1 * d1) + (e2 * d2 + e3 * d3);
      }
      #pragma unroll
      for (int mk = 1; mk < 64; mk <<= 1) {
        Zs += __shfl_xor(Zs, mk);
        E1 += __shfl_xor(E1, mk);
      }
      float invZ = 1.f / Zs;
      kd_acc += LN2 * E1 * invZ - __logf(Zs);
      // sweep 2: recompute e, pav atomic, gumbel ey -> bf16 in place
      float Zy = 0.f;
      #pragma unroll
      for (int K = 0; K < 4; ++K) {
        f16x4 s4 = *(const f16x4*)(Srow + K * 512 + 8 * lane);
        float4 uc = (K == 0) ? ua0 : (K == 1) ? ua1 : (K == 2) ? ua2 : ua3;
        float ey[4];
        #pragma unroll
        for (int j = 0; j < 4; ++j) {
          float d = (float)s4[j] - m;
          float e = __builtin_amdgcn_exp2f(d);
          atomicAdd(&pavacc[K * 256 + 4 * lane + j], e * invZ);
          float uv = (j == 0) ? uc.x : (j == 1) ? uc.y : (j == 2) ? uc.z : uc.w;
          float lg2u = __builtin_amdgcn_logf(uv + 1e-10f);      // log2(u+eps)
          float B = fmaf(-LN2, lg2u, 1e-10f);                   // -ln(u+eps)+eps
          float yv = __builtin_amdgcn_exp2f(d - __builtin_amdgcn_logf(B) - GS2);
          Zy += yv;
          ey[j] = yv;
        }
        uint2 pk;
        pk.x = (unsigned)f2bf(ey[0]) | ((unsigned)f2bf(ey[1]) << 16);
        pk.y = (unsigned)f2bf(ey[2]) | ((unsigned)f2bf(ey[3]) << 16);
        *(uint2*)(Srow + K * 512 + 8 * lane) = pk;
      }
      ua0 = un0; ua1 = un1; ua2 = un2; ua3 = un3;
      Zy = wsum64(Zy);
      if (lane == 0) zys[lr] = Zy;
      __builtin_amdgcn_sched_barrier(0);  // no cross-row hoisting (spill guard)
    }
    bar();  // ey + zys visible

    // ---- PD: z_q = Ey @ codebook ----
    f32x4 dacc = {0.f, 0.f, 0.f, 0.f};
    for (int tt = 0; tt < NTILES; ++tt) {
      const char* tb = cbtp + tt * 17408 + pdOff;
      bf16x8 d0 = *(const bf16x8*)(tb);
      bf16x8 d1 = *(const bf16x8*)(tb + 64);
      bf16x8 d2 = *(const bf16x8*)(tb + 128);
      bf16x8 d3 = *(const bf16x8*)(tb + 192);
      const char* arow_p = Sb + (rb * 16 + l15) * SROWB + (tt * 128 + lg * 8) * 2;
      bf16x8 pa0 = *(const bf16x8*)(arow_p);
      bf16x8 pa1 = *(const bf16x8*)(arow_p + 64);
      bf16x8 pa2 = *(const bf16x8*)(arow_p + 128);
      bf16x8 pa3 = *(const bf16x8*)(arow_p + 192);
      dacc = __builtin_amdgcn_mfma_f32_16x16x32_bf16(pa0, d0, dacc, 0, 0, 0);
      dacc = __builtin_amdgcn_mfma_f32_16x16x32_bf16(pa1, d1, dacc, 0, 0, 0);
      dacc = __builtin_amdgcn_mfma_f32_16x16x32_bf16(pa2, d2, dacc, 0, 0, 0);
      dacc = __builtin_amdgcn_mfma_f32_16x16x32_bf16(pa3, d3, dacc, 0, 0, 0);
    }

    // ---- PE: normalize from regs, write out, kc per-lane ----
    {
      int col = cgrp * 16 + l15;
      int rlb = r0 + rb * 16 + lg * 4;
      #pragma unroll
      for (int rr = 0; rr < 4; ++rr) {
        float v = dacc[rr] / zys[rb * 16 + lg * 4 + rr];
        out[(size_t)(rlb + rr) * DIM + col] = v;
        float zvv = z[(size_t)(rlb + rr) * DIM + col];
        float dq = zvv - v;
        kc_acc += dq * dq;
      }
    }
  }

  // ---- flush: per-block partials (no global atomics) ----
  float kcs = wsum64(kc_acc);
  if (lane == 0) wred[wave] = kd_acc + kcs * weight;
  bar();
  apart[(size_t)blockIdx.x * 1024 + t]       = pavacc[t];
  apart[(size_t)blockIdx.x * 1024 + t + 512] = pavacc[t + 512];
  if (t == 0) {
    float L = 0.f;
    #pragma unroll
    for (int w = 0; w < 8; ++w) L += wred[w];
    lpart[blockIdx.x] = L;
  }
}

// ---------------- reduce avg partials: 32 blocks x 16 rows each ----------------
__global__ __launch_bounds__(512) void gvq_red(char* __restrict__ ws) {
  const float* apart = (const float*)(ws + WS_APART);
  float* avgg        = (float*)(ws + WS_AVG);
  int bb = blockIdx.x, t = threadIdx.x;
  float s0 = 0.f, s1 = 0.f;
  #pragma unroll
  for (int r = 0; r < 16; ++r) {
    float2 v = *(const float2*)(apart + (size_t)(bb * 16 + r) * 1024 + t * 2);
    s0 += v.x; s1 += v.y;
  }
  atomicAdd(&avgg[t * 2], s0);
  atomicAdd(&avgg[t * 2 + 1], s1);
}

// ---------------- final: loss + perplexity ----------------
__global__ __launch_bounds__(256) void gvq_final(const char* __restrict__ ws, float* __restrict__ out) {
  const float* avgg  = (const float*)(ws + WS_AVG);
  const float* lpart = (const float*)(ws + WS_LPART);
  int t = threadIdx.x;
  float s = 0.f;
  #pragma unroll
  for (int i = t; i < SD; i += 256) {
    float a = avgg[i] * (1.f / 65536.f);
    s += a * logf(a + 1e-7f);
  }
  float lp = lpart[t] + lpart[t + 256];
  s = wsum64(s); lp = wsum64(lp);
  __shared__ float ws1[4], ws2[4];
  if ((t & 63) == 0) { ws1[t >> 6] = s; ws2[t >> 6] = lp; }
  __syncthreads();
  if (t == 0) {
    float tot = ws1[0] + ws1[1] + ws1[2] + ws1[3];
    float L   = ws2[0] + ws2[1] + ws2[2] + ws2[3];
    out[(size_t)BS * DIM]     = L * (1.f / 65536.f);
    out[(size_t)BS * DIM + 1] = expf(-tot);
  }
}

extern "C" void kernel_launch(void* const* d_in, const int* in_sizes, int n_in,
                              void* d_out, int out_size, void* d_ws, size_t ws_size,
                              hipStream_t stream) {
  (void)in_sizes; (void)n_in; (void)out_size; (void)ws_size;
  const float* z  = (const float*)d_in[0];
  const float* pq = (const float*)d_in[1];
  const float* cb = (const float*)d_in[2];
  const float* u  = (const float*)d_in[3];
  char* ws   = (char*)d_ws;
  float* out = (float*)d_out;
  hipFuncSetAttribute((const void*)gvq_main, hipFuncAttributeMaxDynamicSharedMemorySize, LDS_BYTES);
  gvq_prep<<<64, 256, 0, stream>>>(cb, ws);
  gvq_main<<<NBLK, NTHREADS, LDS_BYTES, stream>>>(z, pq, u, ws, out);
  gvq_red<<<32, 512, 0, stream>>>(ws);
  gvq_final<<<1, 256, 0, stream>>>(ws, out);
}

// Round 9
// 239.293 us; speedup vs baseline: 2.0907x; 2.0907x over previous
//
#include <hip/hip_runtime.h>

#define BS 65536
#define DIM 64
#define SD 1024
#define NTHREADS 512
#define NBLK 512          // 8 waves/block, each wave owns 16 rows, no mid-kernel barriers
#define LOG2E 1.44269504f
#define LN2   0.69314718f

// LDS layout (bytes)
#define L_PAVW   0        // [8][1024] f32 per-wave avg-prob accumulator (single-writer)
#define L_EYB    32768    // [8][16*80] ey bounce buffer (1280 B/wave, rows stride 80)
#define L_ZY     43008    // [8][16] f32 Zy per row
#define L_WRED   43520    // [8] f32
#define LDS_BYTES 43584

// workspace layout (bytes)
#define WS_CBB   0        // [1024][64] bf16 row-major codebook (128 KB)
#define WS_CBT   131072   // [64][1024] bf16 transposed codebook (128 KB)
#define WS_C2    262144   // [1024] f32
#define WS_AVG   266240   // [1024] f32 accumulator (zeroed by prep)
#define WS_APART 270336   // [512][1024] f32 per-block avg partials (2 MB)
#define WS_LPART 2367488  // [512] f32 per-block loss partials

typedef __attribute__((ext_vector_type(8))) short bf16x8;
typedef __attribute__((ext_vector_type(4))) float f32x4;

__device__ __forceinline__ unsigned short f2bf(float f) {
  union { float f; unsigned int u; } v; v.f = f;
  unsigned int r = v.u + 0x7fffu + ((v.u >> 16) & 1u);
  return (unsigned short)(r >> 16);
}
__device__ __forceinline__ float wsum64(float v) {
  #pragma unroll
  for (int m = 1; m < 64; m <<= 1) v += __shfl_xor(v, m);
  return v;
}
__device__ __forceinline__ bf16x8 pack8(float4 a, float4 b) {
  bf16x8 r;
  r[0]=(short)f2bf(a.x); r[1]=(short)f2bf(a.y); r[2]=(short)f2bf(a.z); r[3]=(short)f2bf(a.w);
  r[4]=(short)f2bf(b.x); r[5]=(short)f2bf(b.y); r[6]=(short)f2bf(b.z); r[7]=(short)f2bf(b.w);
  return r;
}

// ---------------- prep: bf16 codebook (row-major + transposed), c2, zero avgg ----------------
__global__ __launch_bounds__(256) void gvq_prep(const float* __restrict__ cb, char* __restrict__ ws) {
  int gid = blockIdx.x * 256 + threadIdx.x;   // 0..16383
  int j = gid >> 4, dg = gid & 15;
  float4 v = *(const float4*)(cb + j * DIM + dg * 4);
  float s = v.x*v.x + v.y*v.y + v.z*v.z + v.w*v.w;
  s += __shfl_xor(s, 1); s += __shfl_xor(s, 2); s += __shfl_xor(s, 4); s += __shfl_xor(s, 8);
  unsigned short b0 = f2bf(v.x), b1 = f2bf(v.y), b2 = f2bf(v.z), b3 = f2bf(v.w);
  uint2 pk;
  pk.x = (unsigned)b0 | ((unsigned)b1 << 16);
  pk.y = (unsigned)b2 | ((unsigned)b3 << 16);
  *(uint2*)(ws + WS_CBB + j * 128 + dg * 8) = pk;
  unsigned short* tb = (unsigned short*)(ws + WS_CBT);
  int d = dg * 4;
  tb[(d + 0) * 1024 + j] = b0; tb[(d + 1) * 1024 + j] = b1;
  tb[(d + 2) * 1024 + j] = b2; tb[(d + 3) * 1024 + j] = b3;
  if (dg == 0) ((float*)(ws + WS_C2))[j] = s;
  if (gid < SD) ((float*)(ws + WS_AVG))[gid] = 0.f;
}

// ---------------- main: 512 blocks x 8 independent waves x 16 rows ----------------
__global__ __launch_bounds__(NTHREADS, 2) void gvq_main(
    const float* __restrict__ z, const float* __restrict__ pq,
    const float* __restrict__ u, char* __restrict__ ws,
    float* __restrict__ out)
{
  extern __shared__ char smem[];
  const int t    = threadIdx.x;
  const int lane = t & 63;
  const int wave = t >> 6;
  const int l15  = lane & 15;
  const int g    = lane >> 4;          // 0..3

  float* pavw = (float*)(smem + L_PAVW) + wave * 1024;
  char*  eyb  = smem + L_EYB + wave * 1280;
  float* zyw  = (float*)(smem + L_ZY) + wave * 16;
  float* wred = (float*)(smem + L_WRED);

  const char*  cbbp = ws + WS_CBB;
  const char*  cbtp = ws + WS_CBT;
  const float* c2p  = (const float*)(ws + WS_C2);
  float* apart = (float*)(ws + WS_APART);
  float* lpart = (float*)(ws + WS_LPART);

  const int r0 = (blockIdx.x * 8 + wave) * 16;

  const float weight = 0.5f / fmaxf(pq[0], 1e-10f);
  const float w2  = weight * LOG2E;    // log2-domain scale
  const float w22 = 2.f * w2;

  // zero this wave's pav slice (own slice only -> no sync needed)
  #pragma unroll
  for (int i = 0; i < 16; ++i) pavw[lane + 64 * i] = 0.f;

  // ---- z fragment (B-operand layout: row=l15, k=(g*8..g*8+7) and +32) + z2 ----
  const float* zr = z + (size_t)(r0 + l15) * DIM + g * 8;
  float4 za = *(const float4*)(zr);
  float4 zb = *(const float4*)(zr + 4);
  float4 zc = *(const float4*)(zr + 32);
  float4 zd = *(const float4*)(zr + 36);
  bf16x8 zf0 = pack8(za, zb);
  bf16x8 zf1 = pack8(zc, zd);
  float zsq = za.x*za.x+za.y*za.y+za.z*za.z+za.w*za.w
            + zb.x*zb.x+zb.y*zb.y+zb.z*zb.z+zb.w*zb.w
            + zc.x*zc.x+zc.y*zc.y+zc.z*zc.z+zc.w*zc.w
            + zd.x*zd.x+zd.y*zd.y+zd.z*zd.z+zd.w*zd.w;
  zsq += __shfl_xor(zsq, 16); zsq += __shfl_xor(zsq, 32);   // z2 of row l15
  const float zpart = w2 * zsq;

  // ---- pass AB: online max + Zs + E1 (all lane-local; S^T tiles via mfma) ----
  float m = -1e30f, Zs = 0.f, E1 = 0.f;
  for (int tt = 0; tt < 64; ++tt) {
    const char* cp = cbbp + (tt * 16 + l15) * 128 + g * 16;
    bf16x8 cf0 = *(const bf16x8*)(cp);
    bf16x8 cf1 = *(const bf16x8*)(cp + 64);
    f32x4 acc = {0.f, 0.f, 0.f, 0.f};
    acc = __builtin_amdgcn_mfma_f32_16x16x32_bf16(cf0, zf0, acc, 0, 0, 0);
    acc = __builtin_amdgcn_mfma_f32_16x16x32_bf16(cf1, zf1, acc, 0, 0, 0);
    float4 c2v = *(const float4*)(c2p + tt * 16 + g * 4);
    // s2[r] = -w2*(z2 + c2 - 2*dot) ; lane's cb = 16*tt + 4*g + r, row = l15
    float s0 = fmaf(w22, acc[0], -(zpart + w2 * c2v.x));
    float s1 = fmaf(w22, acc[1], -(zpart + w2 * c2v.y));
    float s2 = fmaf(w22, acc[2], -(zpart + w2 * c2v.z));
    float s3 = fmaf(w22, acc[3], -(zpart + w2 * c2v.w));
    float nm = fmaxf(fmaxf(fmaxf(s0, s1), fmaxf(s2, s3)), m);
    float dmx = fminf(nm - m, 60.f);          // guards first-iter inf*0
    float sc = __builtin_amdgcn_exp2f(-dmx);
    E1 = sc * (E1 - dmx * Zs);
    Zs = sc * Zs;
    m = nm;
    float d0 = s0 - m, d1 = s1 - m, d2 = s2 - m, d3 = s3 - m;
    float e0 = __builtin_amdgcn_exp2f(d0), e1 = __builtin_amdgcn_exp2f(d1);
    float e2 = __builtin_amdgcn_exp2f(d2), e3 = __builtin_amdgcn_exp2f(d3);
    Zs += (e0 + e1) + (e2 + e3);
    E1 += (e0 * d0 + e1 * d1) + (e2 * d2 + e3 * d3);
  }
  // merge across the 4 g-groups (same row): flash-style stat merge
  #pragma unroll
  for (int mk = 16; mk < 64; mk <<= 1) {
    float mo = __shfl_xor(m, mk);
    float Zo = __shfl_xor(Zs, mk);
    float Eo = __shfl_xor(E1, mk);
    float M  = fmaxf(m, mo);
    float a  = __builtin_amdgcn_exp2f(m - M);
    float b  = __builtin_amdgcn_exp2f(mo - M);
    float Zn = a * Zs + b * Zo;
    E1 = a * (E1 - (M - m) * Zs) + b * (Eo - (M - mo) * Zo);
    Zs = Zn;
    m = M;
  }
  const float invZ = 1.f / Zs;
  float kd_acc = 0.f;
  if (g == 0) kd_acc = LN2 * (E1 * invZ - __builtin_amdgcn_logf(Zs));

  // ---- pass C: recompute tiles; pav tree; gumbel ey -> LDS bounce -> PV mfma ----
  f32x4 q[4];
  #pragma unroll
  for (int dt = 0; dt < 4; ++dt) q[dt] = (f32x4){0.f, 0.f, 0.f, 0.f};
  float Zy = 0.f;
  const float* up = u + (size_t)(r0 + l15) * SD;

  for (int kt = 0; kt < 32; ++kt) {
    #pragma unroll
    for (int T = 0; T < 2; ++T) {
      const int tt = kt * 2 + T;
      const char* cp = cbbp + (tt * 16 + l15) * 128 + g * 16;
      bf16x8 cf0 = *(const bf16x8*)(cp);
      bf16x8 cf1 = *(const bf16x8*)(cp + 64);
      f32x4 acc = {0.f, 0.f, 0.f, 0.f};
      acc = __builtin_amdgcn_mfma_f32_16x16x32_bf16(cf0, zf0, acc, 0, 0, 0);
      acc = __builtin_amdgcn_mfma_f32_16x16x32_bf16(cf1, zf1, acc, 0, 0, 0);
      float4 c2v = *(const float4*)(c2p + tt * 16 + g * 4);
      float4 u4  = *(const float4*)(up + tt * 16 + g * 4);
      float d0 = fmaf(w22, acc[0], -(zpart + w2 * c2v.x)) - m;
      float d1 = fmaf(w22, acc[1], -(zpart + w2 * c2v.y)) - m;
      float d2 = fmaf(w22, acc[2], -(zpart + w2 * c2v.z)) - m;
      float d3 = fmaf(w22, acc[3], -(zpart + w2 * c2v.w)) - m;
      float e0 = __builtin_amdgcn_exp2f(d0), e1 = __builtin_amdgcn_exp2f(d1);
      float e2 = __builtin_amdgcn_exp2f(d2), e3 = __builtin_amdgcn_exp2f(d3);
      // pav: p = e*invZ, reduce over 16 rows (l15 tree), single-writer RMW
      float p0 = e0 * invZ, p1 = e1 * invZ, p2 = e2 * invZ, p3 = e3 * invZ;
      #pragma unroll
      for (int mk = 1; mk < 16; mk <<= 1) {
        p0 += __shfl_xor(p0, mk); p1 += __shfl_xor(p1, mk);
        p2 += __shfl_xor(p2, mk); p3 += __shfl_xor(p3, mk);
      }
      if (l15 == 0) {
        float4* pp = (float4*)(pavw + tt * 16 + g * 4);
        float4 pv = *pp;
        pv.x += p0; pv.y += p1; pv.z += p2; pv.w += p3;
        *pp = pv;
      }
      // gumbel: ey = e * 2^-24 / (-ln(u+eps)+eps)
      float B0 = fmaf(-LN2, __builtin_amdgcn_logf(u4.x + 1e-10f), 1e-10f);
      float B1 = fmaf(-LN2, __builtin_amdgcn_logf(u4.y + 1e-10f), 1e-10f);
      float B2 = fmaf(-LN2, __builtin_amdgcn_logf(u4.z + 1e-10f), 1e-10f);
      float B3 = fmaf(-LN2, __builtin_amdgcn_logf(u4.w + 1e-10f), 1e-10f);
      float y0 = e0 * (5.9604645e-8f * __builtin_amdgcn_rcpf(B0));
      float y1 = e1 * (5.9604645e-8f * __builtin_amdgcn_rcpf(B1));
      float y2 = e2 * (5.9604645e-8f * __builtin_amdgcn_rcpf(B2));
      float y3 = e3 * (5.9604645e-8f * __builtin_amdgcn_rcpf(B3));
      Zy += (y0 + y1) + (y2 + y3);
      uint2 pk;
      pk.x = (unsigned)f2bf(y0) | ((unsigned)f2bf(y1) << 16);
      pk.y = (unsigned)f2bf(y2) | ((unsigned)f2bf(y3) << 16);
      // bounce write: row-major [row l15][cb&31], stride 80 B
      *(uint2*)(eyb + l15 * 80 + T * 32 + g * 8) = pk;
    }
    // A-frag read (row=l15, k=8g..8g+7) + PV: zq += ey @ cbT
    bf16x8 ef = *(const bf16x8*)(eyb + l15 * 80 + g * 16);
    #pragma unroll
    for (int dt = 0; dt < 4; ++dt) {
      const char* bp = cbtp + (dt * 16 + l15) * 2048 + kt * 64 + g * 16;
      bf16x8 bf = *(const bf16x8*)(bp);
      q[dt] = __builtin_amdgcn_mfma_f32_16x16x32_bf16(ef, bf, q[dt], 0, 0, 0);
    }
  }

  // ---- epilogue: Zy reduce, normalize, out, kc ----
  Zy += __shfl_xor(Zy, 16); Zy += __shfl_xor(Zy, 32);
  if (lane < 16) zyw[lane] = Zy;
  float kc_acc = 0.f;
  {
    float iy0 = 1.f / zyw[4 * g + 0];
    float iy1 = 1.f / zyw[4 * g + 1];
    float iy2 = 1.f / zyw[4 * g + 2];
    float iy3 = 1.f / zyw[4 * g + 3];
    #pragma unroll
    for (int dt = 0; dt < 4; ++dt) {
      int col = dt * 16 + l15;
      #pragma unroll
      for (int r = 0; r < 4; ++r) {
        float iy = (r == 0) ? iy0 : (r == 1) ? iy1 : (r == 2) ? iy2 : iy3;
        int row = r0 + 4 * g + r;
        float v = q[dt][r] * iy;
        out[(size_t)row * DIM + col] = v;
        float zv = z[(size_t)row * DIM + col];
        float dq = zv - v;
        kc_acc += dq * dq;
      }
    }
  }
  float kcs = wsum64(kc_acc);
  float kds = wsum64(kd_acc);
  if (lane == 0) wred[wave] = kds + weight * kcs;

  // ---- single block barrier, then flush partials ----
  __syncthreads();
  {
    const float* pv0 = (const float*)(smem + L_PAVW);
    float s0 = 0.f, s1 = 0.f;
    #pragma unroll
    for (int w = 0; w < 8; ++w) {
      s0 += pv0[w * 1024 + t];
      s1 += pv0[w * 1024 + t + 512];
    }
    apart[(size_t)blockIdx.x * 1024 + t]       = s0;
    apart[(size_t)blockIdx.x * 1024 + t + 512] = s1;
    if (t == 0) {
      float L = 0.f;
      #pragma unroll
      for (int w = 0; w < 8; ++w) L += wred[w];
      lpart[blockIdx.x] = L;
    }
  }
}

// ---------------- reduce avg partials: 32 blocks x 16 rows each ----------------
__global__ __launch_bounds__(512) void gvq_red(char* __restrict__ ws) {
  const float* apart = (const float*)(ws + WS_APART);
  float* avgg        = (float*)(ws + WS_AVG);
  int bb = blockIdx.x, t = threadIdx.x;
  float s0 = 0.f, s1 = 0.f;
  #pragma unroll
  for (int r = 0; r < 16; ++r) {
    float2 v = *(const float2*)(apart + (size_t)(bb * 16 + r) * 1024 + t * 2);
    s0 += v.x; s1 += v.y;
  }
  atomicAdd(&avgg[t * 2], s0);
  atomicAdd(&avgg[t * 2 + 1], s1);
}

// ---------------- final: loss + perplexity ----------------
__global__ __launch_bounds__(256) void gvq_final(const char* __restrict__ ws, float* __restrict__ out) {
  const float* avgg  = (const float*)(ws + WS_AVG);
  const float* lpart = (const float*)(ws + WS_LPART);
  int t = threadIdx.x;
  float s = 0.f;
  #pragma unroll
  for (int i = t; i < SD; i += 256) {
    float a = avgg[i] * (1.f / 65536.f);
    s += a * logf(a + 1e-7f);
  }
  float lp = lpart[t] + lpart[t + 256];
  s = wsum64(s); lp = wsum64(lp);
  __shared__ float ws1[4], ws2[4];
  if ((t & 63) == 0) { ws1[t >> 6] = s; ws2[t >> 6] = lp; }
  __syncthreads();
  if (t == 0) {
    float tot = ws1[0] + ws1[1] + ws1[2] + ws1[3];
    float L   = ws2[0] + ws2[1] + ws2[2] + ws2[3];
    out[(size_t)BS * DIM]     = L * (1.f / 65536.f);
    out[(size_t)BS * DIM + 1] = expf(-tot);
  }
}

extern "C" void kernel_launch(void* const* d_in, const int* in_sizes, int n_in,
                              void* d_out, int out_size, void* d_ws, size_t ws_size,
                              hipStream_t stream) {
  (void)in_sizes; (void)n_in; (void)out_size; (void)ws_size;
  const float* z  = (const float*)d_in[0];
  const float* pq = (const float*)d_in[1];
  const float* cb = (const float*)d_in[2];
  const float* u  = (const float*)d_in[3];
  char* ws   = (char*)d_ws;
  float* out = (float*)d_out;
  gvq_prep<<<64, 256, 0, stream>>>(cb, ws);
  gvq_main<<<NBLK, NTHREADS, LDS_BYTES, stream>>>(z, pq, u, ws, out);
  gvq_red<<<32, 512, 0, stream>>>(ws);
  gvq_final<<<1, 256, 0, stream>>>(ws, out);
}